// Round 5
// baseline (365.792 us; speedup 1.0000x reference)
//
#include <hip/hip_runtime.h>
#include <math.h>

#define C 8192
#define D 1024
#define BATCH 1024
#define PM 0.95f
#define PMC 0.05f
// values pre-scaled by 8 before fp8 quant; dot comes out 64x too big.
// epilogue uses 10/64 = 0.15625 (exact in fp32).
#define INVT_SCALED 0.15625f

typedef unsigned char u8;
typedef __attribute__((ext_vector_type(4))) int i32x4;
typedef __attribute__((ext_vector_type(8))) int i32x8;
typedef __attribute__((ext_vector_type(16))) float f32x16;

#define GLOBAL_AS(p) ((const __attribute__((address_space(1))) void*)(p))
#define LDS_AS(p) ((__attribute__((address_space(3))) void*)(p))

// ---------------------------------------------------------------------------
// EMA + fp8 quantize (x8 pre-scale, RNE via v_cvt_pk_fp8_f32), 8 classes per
// block. Packed fp8 layout for 32x32x64 f8f6f4 fragments:
//   tile (rt=row/32, kc=k/64) at byte (rt*16+kc)*2048; within tile:
//   sub=(k>>4)&1 selects 1KB unit; lane=(row&31)+32*((k>>5)&1); byte lane*16+(k&15).
// A glds of one unit (lane*16B) lands exactly in fragment order.
__global__ __launch_bounds__(256) void ema_split_kernel(const float* __restrict__ feat,
                                                        const int* __restrict__ labels,
                                                        const float* __restrict__ protos,
                                                        u8* __restrict__ P8,
                                                        float* __restrict__ rowsum,
                                                        float* __restrict__ out) {
    __shared__ int sl[BATCH];
    __shared__ int cnt[8];
    __shared__ int mlist[8][64];
    __shared__ float red[4];
    const int t = threadIdx.x;
    const int c8 = blockIdx.x * 8;

    if (blockIdx.x < 32) rowsum[blockIdx.x * 256 + t] = 0.0f;
    if (blockIdx.x == 0 && t == 0) out[0] = 0.0f;

    if (t < 8) cnt[t] = 0;
    for (int i = t; i < BATCH; i += 256) sl[i] = labels[i];
    __syncthreads();
    for (int i = t; i < BATCH; i += 256) {
        const int l = sl[i] - c8;
        if (l >= 0 && l < 8) {
            int p = atomicAdd(&cnt[l], 1);
            if (p < 64) mlist[l][p] = i;
        }
    }
    __syncthreads();
    if (t < 8) {                       // per-class insertion sort -> sample order
        const int n = min(cnt[t], 64);
        for (int a = 1; a < n; ++a) {
            int key = mlist[t][a]; int b = a - 1;
            while (b >= 0 && mlist[t][b] > key) { mlist[t][b + 1] = mlist[t][b]; --b; }
            mlist[t][b + 1] = key;
        }
    }
    __syncthreads();

    const int w = t >> 6, lane = t & 63;
    for (int cc = 0; cc < 8; ++cc) {
        const int c = c8 + cc;
        float4 v = *(const float4*)(protos + (size_t)c * D + t * 4);
        const int n = min(cnt[cc], 64);          // block-uniform
        for (int m = 0; m < n; ++m) {
            const int idx = mlist[cc][m];
            const float4 f = *(const float4*)(feat + (size_t)idx * D + t * 4);
            v.x = v.x * PM + f.x * PMC;
            v.y = v.y * PM + f.y * PMC;
            v.z = v.z * PM + f.z * PMC;
            v.w = v.w * PM + f.w * PMC;
            float ss = v.x * v.x + v.y * v.y + v.z * v.z + v.w * v.w;
            #pragma unroll
            for (int off = 32; off > 0; off >>= 1) ss += __shfl_down(ss, off);
            if (lane == 0) red[w] = ss;
            __syncthreads();
            const float tot = red[0] + red[1] + red[2] + red[3];
            const float inv = 1.0f / fmaxf(sqrtf(tot), 1e-12f);
            v.x *= inv; v.y *= inv; v.z *= inv; v.w *= inv;
            __syncthreads();
        }
        // pack 4 consecutive k as 4 fp8 bytes (one uint store)
        const int k0 = t * 4;
        const int rt = c >> 5, r = c & 31;
        const int kc = k0 >> 6, sub = (k0 >> 4) & 1, h = (k0 >> 5) & 1, jj = k0 & 15;
        const size_t off = (size_t)(rt * 16 + kc) * 2048 + sub * 1024 + (r + 32 * h) * 16 + jj;
        int p = __builtin_amdgcn_cvt_pk_fp8_f32(v.x * 8.0f, v.y * 8.0f, 0, false);
        p = __builtin_amdgcn_cvt_pk_fp8_f32(v.z * 8.0f, v.w * 8.0f, p, true);
        *(unsigned int*)(P8 + off) = (unsigned int)p;
    }
}

// ---------------------------------------------------------------------------
// fp8 Gram, mfma_scale_f32_32x32x64_f8f6f4 (scales=1.0). Block tile 256x256,
// 512 threads = 8 waves (qi in {0,1}, qj in {0..3}), wave tile 128x64 =
// 4x2 tiles of 32x32 (128 AGPR acc). Triangle cover bj>=bi over 32 strips
// (528 blocks); diag blocks mask gi>=gj, so rowsum==sum_neg exactly.
// XCD swizzle: blockIdx%8 = XCD owns strips {r, 31-r, r+8, 23-r} (66 blocks
// each, balanced) so A-strips (1 MB fp8) stay L2-resident per XCD.
// Double-buffered LDS (32 KB/buf), one barrier per BK=64 chunk; chunk k+1
// staged before computing chunk k (glds has a full chunk in flight).
__global__ __launch_bounds__(512, 2) void gram8_kernel(const u8* __restrict__ P8,
                                                       float* __restrict__ rowsum) {
    __shared__ u8 lds[2][32768];     // units 0..15 = A (8 tiles x 2), 16..31 = B
    __shared__ float rpart[256];
    __shared__ float cpart[256];
    const int t = threadIdx.x, w = t >> 6, lane = t & 63;

    // swizzled block -> (bi, bj)
    const int r = blockIdx.x & 7, m = blockIdx.x >> 3;
    const int m0 = 32 - r, m1 = m0 + r + 1, m2 = m1 + 24 - r;
    int bi, bj;
    if (m < m0)      { bi = r;      bj = bi + m; }
    else if (m < m1) { bi = 31 - r; bj = bi + (m - m0); }
    else if (m < m2) { bi = r + 8;  bj = bi + (m - m1); }
    else             { bi = 23 - r; bj = bi + (m - m2); }
    const bool diag = (bi == bj);

    if (t < 256) { rpart[t] = 0.0f; cpart[t] = 0.0f; }

    // 4 staging units per wave; unit u = 8*ur + w; tile u>>1, sub u&1
    const u8* gsrc[4];
    #pragma unroll
    for (int ur = 0; ur < 4; ++ur) {
        const int u = 8 * ur + w;
        const int tIdx = u >> 1, sub = u & 1;
        const int rt = (tIdx < 8) ? (bi * 8 + tIdx) : (bj * 8 + (tIdx - 8));
        gsrc[ur] = P8 + (size_t)rt * 32768 + sub * 1024 + lane * 16;
    }

    const int qi = w & 1, qj = w >> 1;
    f32x16 acc[4][2];
    #pragma unroll
    for (int a = 0; a < 4; ++a)
        #pragma unroll
        for (int b = 0; b < 2; ++b)
            #pragma unroll
            for (int e = 0; e < 16; ++e) acc[a][b][e] = 0.0f;

    // prologue: stage chunk 0 into buffer 0
    #pragma unroll
    for (int ur = 0; ur < 4; ++ur)
        __builtin_amdgcn_global_load_lds(GLOBAL_AS(gsrc[ur]),
                                         LDS_AS(&lds[0][(8 * ur + w) * 1024]), 16, 0, 0);

    for (int kc = 0; kc < 16; ++kc) {
        const int cur = kc & 1;
        __syncthreads();   // own glds (chunk kc) drained; buf cur^1 free
        if (kc < 15) {
            #pragma unroll
            for (int ur = 0; ur < 4; ++ur)
                __builtin_amdgcn_global_load_lds(GLOBAL_AS(gsrc[ur] + (size_t)(kc + 1) * 2048),
                                                 LDS_AS(&lds[cur ^ 1][(8 * ur + w) * 1024]), 16, 0, 0);
        }
        i32x8 af[4], bf[2];
        #pragma unroll
        for (int ti = 0; ti < 4; ++ti) {
            const int at = qi * 4 + ti;
            const i32x4 lo = *(const i32x4*)&lds[cur][at * 2048 + lane * 16];
            const i32x4 hi = *(const i32x4*)&lds[cur][at * 2048 + 1024 + lane * 16];
            af[ti] = __builtin_shufflevector(lo, hi, 0, 1, 2, 3, 4, 5, 6, 7);
        }
        #pragma unroll
        for (int tj = 0; tj < 2; ++tj) {
            const int bt = qj * 2 + tj;
            const i32x4 lo = *(const i32x4*)&lds[cur][16384 + bt * 2048 + lane * 16];
            const i32x4 hi = *(const i32x4*)&lds[cur][16384 + bt * 2048 + 1024 + lane * 16];
            bf[tj] = __builtin_shufflevector(lo, hi, 0, 1, 2, 3, 4, 5, 6, 7);
        }
        #pragma unroll
        for (int ti = 0; ti < 4; ++ti)
            #pragma unroll
            for (int tj = 0; tj < 2; ++tj)
                acc[ti][tj] = __builtin_amdgcn_mfma_scale_f32_32x32x64_f8f6f4(
                    af[ti], bf[tj], acc[ti][tj], 0, 0,
                    0, 0x7F7F7F7F, 0, 0x7F7F7F7F);   // fp8/fp8, scales = 1.0
        __syncthreads();   // frag reads done before buf cur is overwritten
    }

    // epilogue: exp(acc*10/64), diag-block triangle mask, row/col partials
    // C layout (32x32): col = lane&31, row = (reg&3) + 8*(reg>>2) + 4*(lane>>5)
    const int half = lane >> 5, col = lane & 31;
    float csum[2] = {0.0f, 0.0f};
    #pragma unroll
    for (int ti = 0; ti < 4; ++ti) {
        float rs[16];
        #pragma unroll
        for (int reg = 0; reg < 16; ++reg) rs[reg] = 0.0f;
        #pragma unroll
        for (int tj = 0; tj < 2; ++tj) {
            const int lj = qj * 64 + tj * 32 + col;
            #pragma unroll
            for (int reg = 0; reg < 16; ++reg) {
                const int li = qi * 128 + ti * 32 + (reg & 3) + 8 * (reg >> 2) + 4 * half;
                float e = __expf(acc[ti][tj][reg] * INVT_SCALED);
                if (diag && li >= lj) e = 0.0f;      // bi<bj blocks: always li<lj globally
                rs[reg] += e;
                csum[tj] += e;
            }
        }
        #pragma unroll
        for (int reg = 0; reg < 16; ++reg) {
            float v = rs[reg];
            v += __shfl_xor(v, 1); v += __shfl_xor(v, 2); v += __shfl_xor(v, 4);
            v += __shfl_xor(v, 8); v += __shfl_xor(v, 16);
            if (col == 0)
                atomicAdd(&rpart[qi * 128 + ti * 32 + (reg & 3) + 8 * (reg >> 2) + 4 * half], v);
        }
    }
    #pragma unroll
    for (int tj = 0; tj < 2; ++tj) {
        float v = csum[tj];
        v += __shfl_xor(v, 32);
        if (half == 0) atomicAdd(&cpart[qj * 64 + tj * 32 + col], v);
    }
    __syncthreads();
    if (t < 256) atomicAdd(&rowsum[bi * 256 + t], rpart[t]);
    else         atomicAdd(&rowsum[bj * 256 + (t - 256)], cpart[t - 256]);
}

// ---------------------------------------------------------------------------
// rowsum == sum_neg (diag + lower triangle excluded in gram)
__global__ __launch_bounds__(256) void final2_kernel(const float* __restrict__ rowsum,
                                                     float* __restrict__ out) {
    __shared__ float red[4];
    const int t = threadIdx.x;
    const int i = blockIdx.x * 256 + t;
    float v = logf(rowsum[i] * (1.0f / (float)(C - 1)));
    #pragma unroll
    for (int off = 32; off > 0; off >>= 1) v += __shfl_down(v, off);
    if ((t & 63) == 0) red[t >> 6] = v;
    __syncthreads();
    if (t == 0)
        atomicAdd(out, (red[0] + red[1] + red[2] + red[3]) * (1.0f / (float)C));
}

// ---------------------------------------------------------------------------
extern "C" void kernel_launch(void* const* d_in, const int* in_sizes, int n_in,
                              void* d_out, int out_size, void* d_ws, size_t ws_size,
                              hipStream_t stream) {
    const float* feat = (const float*)d_in[0];
    const int* labels = (const int*)d_in[1];
    const float* protos = (const float*)d_in[2];
    float* out = (float*)d_out;
    float* rowsum = (float*)d_ws;               // 32 KB
    u8* P8 = (u8*)((char*)d_ws + 32768);        // 8 MiB packed fp8 protos

    ema_split_kernel<<<C / 8, 256, 0, stream>>>(feat, labels, protos, P8, rowsum, out);
    gram8_kernel<<<528, 512, 0, stream>>>(P8, rowsum);
    final2_kernel<<<C / 256, 256, 0, stream>>>(rowsum, out);
}

// Round 6
// 214.660 us; speedup vs baseline: 1.7041x; 1.7041x over previous
//
#include <hip/hip_runtime.h>
#include <math.h>

#define C 8192
#define D 1024
#define BATCH 1024
#define PM 0.95f
#define PMC 0.05f
// values pre-scaled by 8 before fp8 quant; dot comes out 64x too big.
// epilogue uses 10/64 = 0.15625 (exact in fp32).
#define INVT_SCALED 0.15625f

typedef unsigned char u8;
typedef __attribute__((ext_vector_type(16))) float f32x16;

#define GLOBAL_AS(p) ((const __attribute__((address_space(1))) void*)(p))
#define LDS_AS(p) ((__attribute__((address_space(3))) void*)(p))

// ---------------------------------------------------------------------------
// EMA + fp8 quantize (x8 pre-scale), 8 classes per block. fp8 layout for
// 32x32x16 fp8 MFMA fragments (512-B k-units):
//   element (row c, k) -> P8[((c>>5)*64 + (k>>4))*512 + (((k>>3)&1)*32 + (c&31))*8 + (k&7)]
// A ds_read_b64 at unit_base + lane*8 is exactly one fragment; a glds of
// 1024 B (two consecutive k-units, lane*16) stages them in order.
__global__ __launch_bounds__(256) void ema_split_kernel(const float* __restrict__ feat,
                                                        const int* __restrict__ labels,
                                                        const float* __restrict__ protos,
                                                        u8* __restrict__ P8,
                                                        float* __restrict__ rowsum,
                                                        float* __restrict__ out) {
    __shared__ int sl[BATCH];
    __shared__ int cnt[8];
    __shared__ int mlist[8][64];
    __shared__ float red[4];
    const int t = threadIdx.x;
    const int c8 = blockIdx.x * 8;

    if (blockIdx.x < 32) rowsum[blockIdx.x * 256 + t] = 0.0f;
    if (blockIdx.x == 0 && t == 0) out[0] = 0.0f;

    if (t < 8) cnt[t] = 0;
    for (int i = t; i < BATCH; i += 256) sl[i] = labels[i];
    __syncthreads();
    for (int i = t; i < BATCH; i += 256) {
        const int l = sl[i] - c8;
        if (l >= 0 && l < 8) {
            int p = atomicAdd(&cnt[l], 1);
            if (p < 64) mlist[l][p] = i;
        }
    }
    __syncthreads();
    if (t < 8) {                       // per-class insertion sort -> sample order
        const int n = min(cnt[t], 64);
        for (int a = 1; a < n; ++a) {
            int key = mlist[t][a]; int b = a - 1;
            while (b >= 0 && mlist[t][b] > key) { mlist[t][b + 1] = mlist[t][b]; --b; }
            mlist[t][b + 1] = key;
        }
    }
    __syncthreads();

    const int w = t >> 6, lane = t & 63;
    for (int cc = 0; cc < 8; ++cc) {
        const int c = c8 + cc;
        float4 v = *(const float4*)(protos + (size_t)c * D + t * 4);
        const int n = min(cnt[cc], 64);          // block-uniform
        for (int m = 0; m < n; ++m) {
            const int idx = mlist[cc][m];
            const float4 f = *(const float4*)(feat + (size_t)idx * D + t * 4);
            v.x = v.x * PM + f.x * PMC;
            v.y = v.y * PM + f.y * PMC;
            v.z = v.z * PM + f.z * PMC;
            v.w = v.w * PM + f.w * PMC;
            float ss = v.x * v.x + v.y * v.y + v.z * v.z + v.w * v.w;
            #pragma unroll
            for (int off = 32; off > 0; off >>= 1) ss += __shfl_down(ss, off);
            if (lane == 0) red[w] = ss;
            __syncthreads();
            const float tot = red[0] + red[1] + red[2] + red[3];
            const float inv = 1.0f / fmaxf(sqrtf(tot), 1e-12f);
            v.x *= inv; v.y *= inv; v.z *= inv; v.w *= inv;
            __syncthreads();
        }
        // pack 4 consecutive k as 4 fp8 bytes (one uint store)
        const int k0 = t * 4;
        const int rt = c >> 5, r = c & 31;
        const size_t off = ((size_t)(rt * 64 + (k0 >> 4)) * 512)
                         + (((k0 >> 3) & 1) * 32 + r) * 8 + (k0 & 7);
        int p = __builtin_amdgcn_cvt_pk_fp8_f32(v.x * 8.0f, v.y * 8.0f, 0, false);
        p = __builtin_amdgcn_cvt_pk_fp8_f32(v.z * 8.0f, v.w * 8.0f, p, true);
        *(unsigned int*)(P8 + off) = (unsigned int)p;
    }
}

// ---------------------------------------------------------------------------
// fp8 Gram via mfma_f32_32x32x16_fp8_fp8 (i64 operands -> ds_read_b64, no
// tuple assembly, no spill). Block tile 256x256, 512 threads = 8 waves
// (qi=w&1 over 128 rows, qj=w>>1 over 64 cols), wave tile 128x64 = 8 tiles
// of 32x32 (128 AGPR acc + ~12 operand VGPRs). Triangle cover bj>=bi over
// 32 strips (528 blocks); diag blocks mask li>=lj, so rowsum==sum_neg.
// XCD swizzle: blockIdx%8 owns strips {r,31-r,r+8,23-r} (66 blocks each).
// Double-buffered LDS (16 KB/buf, BK=32), one barrier per chunk; chunk k+1
// staged before computing chunk k.
__global__ __launch_bounds__(512, 2) void gram8_kernel(const u8* __restrict__ P8,
                                                       float* __restrict__ rowsum) {
    __shared__ u8 lds[2][16384];     // per buf: A tiles 0..7 @ u*1KB, B @ 8KB+
    __shared__ float rpart[256];
    __shared__ float cpart[256];
    const int t = threadIdx.x, w = t >> 6, lane = t & 63;

    // swizzled block -> (bi, bj)
    const int r = blockIdx.x & 7, m = blockIdx.x >> 3;
    const int m0 = 32 - r, m1 = m0 + r + 1, m2 = m1 + 24 - r;
    int bi, bj;
    if (m < m0)      { bi = r;      bj = bi + m; }
    else if (m < m1) { bi = 31 - r; bj = bi + (m - m0); }
    else if (m < m2) { bi = r + 8;  bj = bi + (m - m1); }
    else             { bi = 23 - r; bj = bi + (m - m2); }
    const bool diag = (bi == bj);

    if (t < 256) { rpart[t] = 0.0f; cpart[t] = 0.0f; }

    // 2 staging units (1 KB glds each) per wave; unit u = 2*w + ur
    const u8* gsrc[2];
    #pragma unroll
    for (int ur = 0; ur < 2; ++ur) {
        const int u = 2 * w + ur;
        const int rt = (u < 8) ? (bi * 8 + u) : (bj * 8 + (u - 8));
        gsrc[ur] = P8 + (size_t)rt * 32768 + lane * 16;
    }

    const int qi = w & 1, qj = w >> 1;
    f32x16 acc[4][2];
    #pragma unroll
    for (int a = 0; a < 4; ++a)
        #pragma unroll
        for (int b = 0; b < 2; ++b)
            #pragma unroll
            for (int e = 0; e < 16; ++e) acc[a][b][e] = 0.0f;

    // prologue: stage chunk 0 into buffer 0
    #pragma unroll
    for (int ur = 0; ur < 2; ++ur)
        __builtin_amdgcn_global_load_lds(GLOBAL_AS(gsrc[ur]),
                                         LDS_AS(&lds[0][(2 * w + ur) * 1024]), 16, 0, 0);

    for (int kc = 0; kc < 32; ++kc) {
        const int cur = kc & 1;
        __syncthreads();   // own glds (chunk kc) drained; buf cur^1 free
        if (kc < 31) {
            #pragma unroll
            for (int ur = 0; ur < 2; ++ur)
                __builtin_amdgcn_global_load_lds(GLOBAL_AS(gsrc[ur] + (size_t)(kc + 1) * 1024),
                                                 LDS_AS(&lds[cur ^ 1][(2 * w + ur) * 1024]), 16, 0, 0);
        }
        #pragma unroll
        for (int kcl = 0; kcl < 2; ++kcl) {
            long af[4], bf[2];
            #pragma unroll
            for (int ti = 0; ti < 4; ++ti)
                af[ti] = *(const long*)&lds[cur][(qi * 4 + ti) * 1024 + kcl * 512 + lane * 8];
            #pragma unroll
            for (int tj = 0; tj < 2; ++tj)
                bf[tj] = *(const long*)&lds[cur][8192 + (qj * 2 + tj) * 1024 + kcl * 512 + lane * 8];
            #pragma unroll
            for (int ti = 0; ti < 4; ++ti)
                #pragma unroll
                for (int tj = 0; tj < 2; ++tj)
                    acc[ti][tj] = __builtin_amdgcn_mfma_f32_32x32x16_fp8_fp8(
                        af[ti], bf[tj], acc[ti][tj], 0, 0, 0);
        }
        __syncthreads();   // frag reads done before buf cur is overwritten
    }

    // epilogue: exp(acc*10/64), diag-block triangle mask, row/col partials
    // C layout (32x32): col = lane&31, row = (reg&3) + 8*(reg>>2) + 4*(lane>>5)
    const int half = lane >> 5, col = lane & 31;
    float csum[2] = {0.0f, 0.0f};
    #pragma unroll
    for (int ti = 0; ti < 4; ++ti) {
        float rs[16];
        #pragma unroll
        for (int reg = 0; reg < 16; ++reg) rs[reg] = 0.0f;
        #pragma unroll
        for (int tj = 0; tj < 2; ++tj) {
            const int lj = qj * 64 + tj * 32 + col;
            #pragma unroll
            for (int reg = 0; reg < 16; ++reg) {
                const int li = qi * 128 + ti * 32 + (reg & 3) + 8 * (reg >> 2) + 4 * half;
                float e = __expf(acc[ti][tj][reg] * INVT_SCALED);
                if (diag && li >= lj) e = 0.0f;      // bi<bj blocks: always li<lj globally
                rs[reg] += e;
                csum[tj] += e;
            }
        }
        #pragma unroll
        for (int reg = 0; reg < 16; ++reg) {
            float v = rs[reg];
            v += __shfl_xor(v, 1); v += __shfl_xor(v, 2); v += __shfl_xor(v, 4);
            v += __shfl_xor(v, 8); v += __shfl_xor(v, 16);
            if (col == 0)
                atomicAdd(&rpart[qi * 128 + ti * 32 + (reg & 3) + 8 * (reg >> 2) + 4 * half], v);
        }
    }
    #pragma unroll
    for (int tj = 0; tj < 2; ++tj) {
        float v = csum[tj];
        v += __shfl_xor(v, 32);
        if (half == 0) atomicAdd(&cpart[qj * 64 + tj * 32 + col], v);
    }
    __syncthreads();
    if (t < 256) atomicAdd(&rowsum[bi * 256 + t], rpart[t]);
    else         atomicAdd(&rowsum[bj * 256 + (t - 256)], cpart[t - 256]);
}

// ---------------------------------------------------------------------------
// rowsum == sum_neg (diag + lower triangle excluded in gram)
__global__ __launch_bounds__(256) void final2_kernel(const float* __restrict__ rowsum,
                                                     float* __restrict__ out) {
    __shared__ float red[4];
    const int t = threadIdx.x;
    const int i = blockIdx.x * 256 + t;
    float v = logf(rowsum[i] * (1.0f / (float)(C - 1)));
    #pragma unroll
    for (int off = 32; off > 0; off >>= 1) v += __shfl_down(v, off);
    if ((t & 63) == 0) red[t >> 6] = v;
    __syncthreads();
    if (t == 0)
        atomicAdd(out, (red[0] + red[1] + red[2] + red[3]) * (1.0f / (float)C));
}

// ---------------------------------------------------------------------------
extern "C" void kernel_launch(void* const* d_in, const int* in_sizes, int n_in,
                              void* d_out, int out_size, void* d_ws, size_t ws_size,
                              hipStream_t stream) {
    const float* feat = (const float*)d_in[0];
    const int* labels = (const int*)d_in[1];
    const float* protos = (const float*)d_in[2];
    float* out = (float*)d_out;
    float* rowsum = (float*)d_ws;               // 32 KB
    u8* P8 = (u8*)((char*)d_ws + 32768);        // 8 MiB packed fp8 protos

    ema_split_kernel<<<C / 8, 256, 0, stream>>>(feat, labels, protos, P8, rowsum, out);
    gram8_kernel<<<528, 512, 0, stream>>>(P8, rowsum);
    final2_kernel<<<C / 256, 256, 0, stream>>>(rowsum, out);
}